// Round 1
// baseline (129.528 us; speedup 1.0000x reference)
//
#include <hip/hip_runtime.h>

#define IMG_H 512
#define IMG_W 512
#define BATCH 32
#define TW 256          // tile width (one thread per column)
#define TH 64           // tile height (output rows per block)
#define NROWS (TH + 6)  // input rows streamed per tile
#define LW (TW + 6)     // loaded row width incl. halo

__device__ __forceinline__ float ssim_val(float mu_x, float mu_y,
                                          float exx, float eyy, float exy) {
  const float C1 = 0.0001f;   // 0.01^2
  const float C2 = 0.0009f;   // 0.03^2
  float mx2 = mu_x * mu_x;
  float my2 = mu_y * mu_y;
  float mxy = mu_x * mu_y;
  float sxx = exx - mx2;
  float syy = eyy - my2;
  float sxy = exy - mxy;
  float num = (2.0f * mxy + C1) * (2.0f * sxy + C2);
  float den = (mx2 + my2 + C1) * (sxx + syy + C2);
  return num / den;
}

__global__ __launch_bounds__(256) void ssim_kernel(
    const float* __restrict__ X, const float* __restrict__ Y,
    const float* __restrict__ K, double* __restrict__ acc_out) {
  __shared__ float xr[2][LW + 2];
  __shared__ float yr[2][LW + 2];
  __shared__ float warp_sums[4];

  const int t = threadIdx.x;
  const int x0 = blockIdx.x * TW;
  const int y0 = blockIdx.y * TH;
  const float* Xb = X + (size_t)blockIdx.z * (IMG_H * IMG_W);
  const float* Yb = Y + (size_t)blockIdx.z * (IMG_H * IMG_W);

  // Recover exact separable 1D weights from center row of the provided 7x7:
  // k[3][j] = w3*w_j with sum_j w_j = 1 => w_j = k[3][j] / sum_j k[3][j].
  float w[7];
  {
    float rs = 0.0f;
#pragma unroll
    for (int j = 0; j < 7; ++j) { w[j] = K[3 * 7 + j]; rs += w[j]; }
    float inv = 1.0f / rs;
#pragma unroll
    for (int j = 0; j < 7; ++j) w[j] *= inv;
  }

  // 7-slot ring of 5-channel vertical accumulators (all indices constant
  // after unroll-by-14 so these stay in registers).
  float acc[7][5];
#pragma unroll
  for (int s = 0; s < 7; ++s)
#pragma unroll
    for (int c = 0; c < 5; ++c) acc[s][c] = 0.0f;

  float tsum = 0.0f;

  // Row prefetch registers
  float pxa, pya, pxb, pyb;
  auto load_row = [&](int r) {
    int gy = y0 - 3 + r;
    bool rowok = (0 <= gy) && (gy < IMG_H);
    int g1 = x0 - 3 + t;
    pxa = 0.0f; pya = 0.0f; pxb = 0.0f; pyb = 0.0f;
    if (rowok) {
      const float* xrow = Xb + (size_t)gy * IMG_W;
      const float* yrow = Yb + (size_t)gy * IMG_W;
      if (0 <= g1 && g1 < IMG_W) { pxa = xrow[g1]; pya = yrow[g1]; }
      if (t < 6) {
        int g2 = g1 + TW;
        if (g2 < IMG_W) { pxb = xrow[g2]; pyb = yrow[g2]; }
      }
    }
  };

  load_row(0);

  for (int rb = 0; rb < NROWS; rb += 14) {  // 70 = 5 * 14; rb % 14 == 0
#pragma unroll
    for (int rr = 0; rr < 14; ++rr) {
      const int r = rb + rr;       // runtime, but r % 7 == rr % 7 (rb % 7 == 0)
      const int buf = rr & 1;      // rb even => parity static

      // store prefetched row to LDS
      xr[buf][t] = pxa;
      yr[buf][t] = pya;
      if (t < 6) { xr[buf][t + TW] = pxb; yr[buf][t + TW] = pyb; }

      // issue next row's loads (consumed at next iteration's store)
      if (r + 1 < NROWS) load_row(r + 1);

      __syncthreads();

      // horizontal 7-tap for 5 channels
      float hx = 0.0f, hy = 0.0f, hxx = 0.0f, hyy = 0.0f, hxy = 0.0f;
#pragma unroll
      for (int k = 0; k < 7; ++k) {
        float xv = xr[buf][t + k];
        float yv = yr[buf][t + k];
        float wx = w[k] * xv;
        float wy = w[k] * yv;
        hx += wx;
        hy += wy;
        hxx = fmaf(wx, xv, hxx);
        hyy = fmaf(wy, yv, hyy);
        hxy = fmaf(wx, yv, hxy);
      }

      // vertical scatter into the ring (slot indices constant-folded)
#pragma unroll
      for (int tt = 0; tt < 7; ++tt) {
        const int slot = ((rr - tt) % 7 + 7) % 7;
        const int o = r - tt;
        if (o >= 0 && o < TH) {
          const float wt = w[tt];
          acc[slot][0] = fmaf(wt, hx, acc[slot][0]);
          acc[slot][1] = fmaf(wt, hy, acc[slot][1]);
          acc[slot][2] = fmaf(wt, hxx, acc[slot][2]);
          acc[slot][3] = fmaf(wt, hyy, acc[slot][3]);
          acc[slot][4] = fmaf(wt, hxy, acc[slot][4]);
        }
      }

      // output row r-6 is complete
      const int oc = r - 6;
      if (oc >= 0) {
        const int slot = (rr + 1) % 7;  // == oc % 7 since rb % 7 == 0
        tsum += ssim_val(acc[slot][0], acc[slot][1], acc[slot][2],
                         acc[slot][3], acc[slot][4]);
#pragma unroll
        for (int c = 0; c < 5; ++c) acc[slot][c] = 0.0f;
      }
      // no trailing sync needed: double-buffered rows, one sync per row
    }
  }

  // block reduction: wave64 shuffle -> LDS -> one double atomic per block
#pragma unroll
  for (int off = 32; off > 0; off >>= 1) tsum += __shfl_down(tsum, off);
  if ((t & 63) == 0) warp_sums[t >> 6] = tsum;
  __syncthreads();
  if (t == 0) {
    float bsum = warp_sums[0] + warp_sums[1] + warp_sums[2] + warp_sums[3];
    atomicAdd(acc_out, (double)bsum);
  }
}

__global__ void ssim_init(double* acc) { acc[0] = 0.0; }

__global__ void ssim_final(const double* __restrict__ acc, float* __restrict__ out) {
  out[0] = (float)(acc[0] * (1.0 / (double)((size_t)BATCH * IMG_H * IMG_W)));
}

extern "C" void kernel_launch(void* const* d_in, const int* in_sizes, int n_in,
                              void* d_out, int out_size, void* d_ws, size_t ws_size,
                              hipStream_t stream) {
  const float* X = (const float*)d_in[0];
  const float* Y = (const float*)d_in[1];
  const float* K = (const float*)d_in[2];
  float* out = (float*)d_out;
  double* acc = (double*)d_ws;

  hipLaunchKernelGGL(ssim_init, dim3(1), dim3(1), 0, stream, acc);
  dim3 grid(IMG_W / TW, IMG_H / TH, BATCH);  // (2, 8, 32)
  hipLaunchKernelGGL(ssim_kernel, grid, dim3(256), 0, stream, X, Y, K, acc);
  hipLaunchKernelGGL(ssim_final, dim3(1), dim3(1), 0, stream, acc, out);
}